// Round 3
// baseline (228.533 us; speedup 1.0000x reference)
//
#include <hip/hip_runtime.h>

#define BATCH 8
#define NROW  2048
#define DIM   512
#define BM 128
#define BN 128
#define BK 32

typedef __bf16 bf16x8 __attribute__((ext_vector_type(8)));
typedef float  f32x4  __attribute__((ext_vector_type(4)));

typedef __attribute__((address_space(3))) void       lds_t;
typedef const __attribute__((address_space(1))) void gmem_t;

// round-to-nearest-even fp32 -> bf16 bits
__device__ __forceinline__ unsigned short f2bf(float f) {
    unsigned int u = __float_as_uint(f);
    u += 0x7FFFu + ((u >> 16) & 1u);
    return (unsigned short)(u >> 16);
}

// One wave per row: cast row to bf16 (coalesced) + compute 1/||row|| in fp32.
__global__ __launch_bounds__(256) void prep_kernel(
    const float* __restrict__ x, const float* __restrict__ y,
    unsigned short* __restrict__ xbf, unsigned short* __restrict__ ybf,
    float* __restrict__ rxn, float* __restrict__ ryn)
{
    const int wave = threadIdx.x >> 6;
    const int lane = threadIdx.x & 63;
    const int row  = blockIdx.x * 4 + wave;           // 0..16383

    const float* src; unsigned short* dst; float* rn;
    if (blockIdx.y == 0) { src = x; dst = xbf; rn = rxn; }
    else                 { src = y; dst = ybf; rn = ryn; }

    const float4* s4 = (const float4*)(src + (size_t)row * DIM);
    ushort4*      d4 = (ushort4*)(dst + (size_t)row * DIM);

    float ss = 0.f;
#pragma unroll
    for (int h = 0; h < 2; ++h) {
        float4 v = s4[h * 64 + lane];
        ss += v.x * v.x + v.y * v.y + v.z * v.z + v.w * v.w;
        ushort4 o;
        o.x = f2bf(v.x); o.y = f2bf(v.y); o.z = f2bf(v.z); o.w = f2bf(v.w);
        d4[h * 64 + lane] = o;
    }
#pragma unroll
    for (int off = 32; off; off >>= 1) ss += __shfl_xor(ss, off, 64);
    if (lane == 0) rn[row] = 1.0f / sqrtf(ss);   // norms ~22.6, eps never binds
}

// 128x128 tile, BK=32, 4 waves (2x2), each wave 64x64 via 4x4 frags of
// mfma_f32_16x16x32_bf16. global_load_lds width-16 staging, linear LDS.
__global__ __launch_bounds__(256) void gemm_kernel(
    const __bf16* __restrict__ xbf, const __bf16* __restrict__ ybf,
    const float* __restrict__ rxn, const float* __restrict__ ryn,
    float* __restrict__ out)
{
    __shared__ __bf16 As[BM * BK];
    __shared__ __bf16 Bs[BN * BK];

    const int b    = blockIdx.y;
    const int bm   = blockIdx.x & 15;
    const int bn   = blockIdx.x >> 4;
    const int tid  = threadIdx.x;
    const int wave = tid >> 6;
    const int lane = tid & 63;
    const int wr   = wave >> 1;      // 0..1
    const int wc   = wave & 1;       // 0..1

    const __bf16* Ab = xbf + ((size_t)b * NROW + bm * BM) * DIM;
    const __bf16* Bb = ybf + ((size_t)b * NROW + bn * BN) * DIM;

    // staging geometry: wave w covers tile rows [w*32, w*32+32) in two
    // 16-row global_load_lds calls; lane l -> row +(l>>2), k-elems (l&3)*8.
    const int sr  = wave * 32 + (lane >> 2);
    const int sc  = (lane & 3) * 8;

    f32x4 acc[4][4] = {};

    for (int k0 = 0; k0 < DIM; k0 += BK) {
        __builtin_amdgcn_global_load_lds(
            (gmem_t*)(Ab + (size_t)sr * DIM + k0 + sc),
            (lds_t*)(As + (wave * 32) * BK), 16, 0, 0);
        __builtin_amdgcn_global_load_lds(
            (gmem_t*)(Ab + (size_t)(sr + 16) * DIM + k0 + sc),
            (lds_t*)(As + (wave * 32 + 16) * BK), 16, 0, 0);
        __builtin_amdgcn_global_load_lds(
            (gmem_t*)(Bb + (size_t)sr * DIM + k0 + sc),
            (lds_t*)(Bs + (wave * 32) * BK), 16, 0, 0);
        __builtin_amdgcn_global_load_lds(
            (gmem_t*)(Bb + (size_t)(sr + 16) * DIM + k0 + sc),
            (lds_t*)(Bs + (wave * 32 + 16) * BK), 16, 0, 0);

        __syncthreads();   // drains vmcnt -> tiles visible

        bf16x8 af[4], bfr[4];
#pragma unroll
        for (int m = 0; m < 4; ++m)
            af[m] = *(const bf16x8*)(As + (wr * 64 + m * 16 + (lane & 15)) * BK + (lane >> 4) * 8);
#pragma unroll
        for (int n = 0; n < 4; ++n)
            bfr[n] = *(const bf16x8*)(Bs + (wc * 64 + n * 16 + (lane & 15)) * BK + (lane >> 4) * 8);

#pragma unroll
        for (int m = 0; m < 4; ++m)
#pragma unroll
            for (int n = 0; n < 4; ++n)
                acc[m][n] = __builtin_amdgcn_mfma_f32_16x16x32_bf16(
                    af[m], bfr[n], acc[m][n], 0, 0, 0);

        __syncthreads();   // all reads done before next stage overwrites
    }

    // epilogue: C/D frag layout col=lane&15, row=(lane>>4)*4+j  [m89]
    const int col = lane & 15;
    const int r4  = (lane >> 4) * 4;
    const int gmb = bm * BM + wr * 64;
    const int gnb = bn * BN + wc * 64;
    float* C = out + (size_t)b * NROW * NROW;
    const float* rxb = rxn + b * NROW;
    const float* ryb = ryn + b * NROW;

#pragma unroll
    for (int n = 0; n < 4; ++n) {
        const float ry = ryb[gnb + n * 16 + col];
#pragma unroll
        for (int m = 0; m < 4; ++m) {
#pragma unroll
            for (int j = 0; j < 4; ++j) {
                const int gm = gmb + m * 16 + r4 + j;
                C[(size_t)gm * NROW + gnb + n * 16 + col] =
                    acc[m][n][j] * rxb[gm] * ry;
            }
        }
    }
}

extern "C" void kernel_launch(void* const* d_in, const int* in_sizes, int n_in,
                              void* d_out, int out_size, void* d_ws, size_t ws_size,
                              hipStream_t stream)
{
    const float* x = (const float*)d_in[0];
    const float* y = (const float*)d_in[1];
    float* out = (float*)d_out;

    char* ws = (char*)d_ws;
    unsigned short* xbf = (unsigned short*)ws;                            // 16 MiB
    unsigned short* ybf = (unsigned short*)(ws + ((size_t)16 << 20));     // 16 MiB
    float* rxn = (float*)(ws + ((size_t)32 << 20));                       // 64 KiB
    float* ryn = rxn + BATCH * NROW;                                      // 64 KiB

    prep_kernel<<<dim3(4096, 2), 256, 0, stream>>>(x, y, xbf, ybf, rxn, ryn);
    gemm_kernel<<<dim3(256, BATCH), 256, 0, stream>>>(
        (const __bf16*)xbf, (const __bf16*)ybf, rxn, ryn, out);
}

// Round 4
// 215.528 us; speedup vs baseline: 1.0603x; 1.0603x over previous
//
#include <hip/hip_runtime.h>

#define BATCH 8
#define NROW  2048
#define DIM   512

typedef __bf16 bf16x8 __attribute__((ext_vector_type(8)));
typedef float  f32x4  __attribute__((ext_vector_type(4)));

typedef __attribute__((address_space(3))) void       lds_t;
typedef const __attribute__((address_space(1))) void gmem_t;

// round-to-nearest-even fp32 -> bf16 bits
__device__ __forceinline__ unsigned short f2bf(float f) {
    unsigned int u = __float_as_uint(f);
    u += 0x7FFFu + ((u >> 16) & 1u);
    return (unsigned short)(u >> 16);
}

// One wave per row: cast row to bf16 (coalesced) + compute 1/||row|| in fp32.
__global__ __launch_bounds__(256) void prep_kernel(
    const float* __restrict__ x, const float* __restrict__ y,
    unsigned short* __restrict__ xbf, unsigned short* __restrict__ ybf,
    float* __restrict__ rxn, float* __restrict__ ryn)
{
    const int wave = threadIdx.x >> 6;
    const int lane = threadIdx.x & 63;
    const int row  = blockIdx.x * 4 + wave;

    const float* src; unsigned short* dst; float* rn;
    if (blockIdx.y == 0) { src = x; dst = xbf; rn = rxn; }
    else                 { src = y; dst = ybf; rn = ryn; }

    const float4* s4 = (const float4*)(src + (size_t)row * DIM);
    ushort4*      d4 = (ushort4*)(dst + (size_t)row * DIM);

    float ss = 0.f;
#pragma unroll
    for (int h = 0; h < 2; ++h) {
        float4 v = s4[h * 64 + lane];
        ss += v.x * v.x + v.y * v.y + v.z * v.z + v.w * v.w;
        ushort4 o;
        o.x = f2bf(v.x); o.y = f2bf(v.y); o.z = f2bf(v.z); o.w = f2bf(v.w);
        d4[h * 64 + lane] = o;
    }
#pragma unroll
    for (int off = 32; off; off >>= 1) ss += __shfl_xor(ss, off, 64);
    if (lane == 0) rn[row] = 1.0f / sqrtf(ss);
}

// ---------------- 256x256 tile, BK=64, 8-wave, 8-phase pipelined GEMM -------
// LDS: 8 half-buffers of 16KB: index (par<<2)|(X<<1)|k, X: A=0,B=1.
// Half-buffer layout: 16 subtiles [16 rows][32 bf16] of 1024B, st_16x32
// swizzle: col-bytes ^= 32 when (row&15)>=8. Staged via linear-dest
// global_load_lds with inverse-swizzled per-lane GLOBAL source (rule #21).

#define STAGE(Xp, Xi, K, T)                                                  \
  { char* hb_ = sm + (((((T) & 1) << 2) | ((Xi) << 1) | (K)) << 14);         \
    __builtin_amdgcn_global_load_lds(                                        \
      (gmem_t*)((Xp) + (size_t)vr0 * DIM + (T) * 64 + (K) * 32 + vc),        \
      (lds_t*)(hb_ + wave * 1024), 16, 0, 0);                                \
    __builtin_amdgcn_global_load_lds(                                        \
      (gmem_t*)((Xp) + (size_t)vr1 * DIM + (T) * 64 + (K) * 32 + vc),        \
      (lds_t*)(hb_ + 8192 + wave * 1024), 16, 0, 0); }

#define LDSA(M, KS, PAR) \
  (*(const bf16x8*)(sm + ((((PAR) << 2) | (KS)) << 14) + ((wm * 8 + (M)) << 10) + rb))
#define LDSB(N, KS, PAR) \
  (*(const bf16x8*)(sm + ((((PAR) << 2) | 2 | (KS)) << 14) + ((wn * 4 + (N)) << 10) + rb))

#define PHASE(PAR, MH, KS, READB, STAGE_STMT, VM_STMT)                       \
  { __builtin_amdgcn_sched_barrier(0);                                       \
    bf16x8 a0 = LDSA((MH)*4+0, KS, PAR), a1 = LDSA((MH)*4+1, KS, PAR),       \
           a2 = LDSA((MH)*4+2, KS, PAR), a3 = LDSA((MH)*4+3, KS, PAR);       \
    if (READB) { bfr[0] = LDSB(0, KS, PAR); bfr[1] = LDSB(1, KS, PAR);       \
                 bfr[2] = LDSB(2, KS, PAR); bfr[3] = LDSB(3, KS, PAR); }     \
    STAGE_STMT;                                                              \
    __builtin_amdgcn_s_barrier();                                            \
    asm volatile("s_waitcnt lgkmcnt(0)" ::: "memory");                       \
    VM_STMT;                                                                 \
    __builtin_amdgcn_sched_barrier(0);                                       \
    __builtin_amdgcn_s_setprio(1);                                           \
    _Pragma("unroll")                                                        \
    for (int n = 0; n < 4; ++n) {                                            \
      acc[(MH)*4+0][n] = __builtin_amdgcn_mfma_f32_16x16x32_bf16(a0, bfr[n], acc[(MH)*4+0][n], 0, 0, 0); \
      acc[(MH)*4+1][n] = __builtin_amdgcn_mfma_f32_16x16x32_bf16(a1, bfr[n], acc[(MH)*4+1][n], 0, 0, 0); \
      acc[(MH)*4+2][n] = __builtin_amdgcn_mfma_f32_16x16x32_bf16(a2, bfr[n], acc[(MH)*4+2][n], 0, 0, 0); \
      acc[(MH)*4+3][n] = __builtin_amdgcn_mfma_f32_16x16x32_bf16(a3, bfr[n], acc[(MH)*4+3][n], 0, 0, 0); \
    }                                                                        \
    __builtin_amdgcn_s_setprio(0);                                           \
    __builtin_amdgcn_sched_barrier(0);                                       \
    __builtin_amdgcn_s_barrier(); }

#define VM6 asm volatile("s_waitcnt vmcnt(6)" ::: "memory")
#define VM0 asm volatile("s_waitcnt vmcnt(0)" ::: "memory")

__global__ __launch_bounds__(512) void gemm_kernel(
    const __bf16* __restrict__ xbf, const __bf16* __restrict__ ybf,
    const float* __restrict__ rxn, const float* __restrict__ ryn,
    float* __restrict__ out)
{
    extern __shared__ char sm[];
    const int tid  = threadIdx.x;
    const int lane = tid & 63;
    const int wave = tid >> 6;
    const int wm   = wave >> 2;     // 0..1  (M half)
    const int wn   = wave & 3;      // 0..3  (N quarter)

    // bijective XCD swizzle: nwg=512, 8 XCDs, 64 blocks each -> batch b == XCD
    const int bid = blockIdx.x;
    const int wg  = (bid & 7) * 64 + (bid >> 3);
    const int b   = wg >> 6;
    const int bm  = (wg >> 3) & 7;
    const int bn  = wg & 7;

    const __bf16* Ap = xbf + ((size_t)b * NROW + bm * 256) * DIM;
    const __bf16* Bp = ybf + ((size_t)b * NROW + bn * 256) * DIM;

    // staging per-lane source geometry (inverse-swizzled global address)
    const int vr0 = wave * 16 + (lane >> 2);          // rows 0..127
    const int vr1 = vr0 + 128;                        // rows 128..255
    const int vc  = ((lane & 3) * 8) ^ ((lane & 32) ? 16 : 0);   // bf16 units
    // read per-lane base byte within a half-buffer subtile-row
    const int rb  = (lane & 15) * 64 + (((lane >> 4) * 16) ^ ((lane & 8) ? 32 : 0));

    // ---- prologue: B-k0(0) A-k0(0) B-k1(0) A-k1(0) B-k0(1) A-k0(1) B-k1(1)
    STAGE(Bp, 1, 0, 0) STAGE(Ap, 0, 0, 0) STAGE(Bp, 1, 1, 0) STAGE(Ap, 0, 1, 0)
    STAGE(Bp, 1, 0, 1) STAGE(Ap, 0, 0, 1) STAGE(Bp, 1, 1, 1)
    VM6;
    __builtin_amdgcn_sched_barrier(0);
    __builtin_amdgcn_s_barrier();

    f32x4 acc[8][4] = {};
    bf16x8 bfr[4];

    for (int i = 0; i < 4; ++i) {
        const int t1 = 2 * i + 1, t2 = 2 * i + 2, t3 = 2 * i + 3;
        const bool full = (i < 3);
        // tile T0 = 2i (par 0)
        PHASE(0, 0, 0, 1, STAGE(Ap, 0, 1, t1), )
        PHASE(0, 1, 0, 0, if (full) STAGE(Bp, 1, 0, t2), )
        PHASE(0, 0, 1, 1, if (full) STAGE(Ap, 0, 0, t2), )
        PHASE(0, 1, 1, 0, if (full) STAGE(Bp, 1, 1, t2), if (full) { VM6; } else { VM0; })
        // tile T1 = 2i+1 (par 1)
        PHASE(1, 0, 0, 1, if (full) STAGE(Ap, 0, 1, t2), )
        PHASE(1, 1, 0, 0, if (full) STAGE(Bp, 1, 0, t3), )
        PHASE(1, 0, 1, 1, if (full) STAGE(Ap, 0, 0, t3), )
        PHASE(1, 1, 1, 0, if (full) STAGE(Bp, 1, 1, t3), if (full) { VM6; })
    }

    // ---- epilogue: C/D layout col=lane&15, row=(lane>>4)*4+j  [m89]
    const int col = lane & 15;
    const int r4  = (lane >> 4) * 4;
    const int gm0 = bm * 256 + wm * 128;
    const int gn0 = bn * 256 + wn * 64;
    float* C = out + (size_t)b * NROW * NROW;
    const float* rxb = rxn + b * NROW;
    const float* ryb = ryn + b * NROW;

    float ryv[4];
#pragma unroll
    for (int n = 0; n < 4; ++n) ryv[n] = ryb[gn0 + n * 16 + col];

#pragma unroll
    for (int m = 0; m < 8; ++m) {
#pragma unroll
        for (int j = 0; j < 4; ++j) {
            const int gm = gm0 + m * 16 + r4 + j;
            const float rx = rxb[gm];
            float* Crow = C + (size_t)gm * NROW + gn0;
#pragma unroll
            for (int n = 0; n < 4; ++n)
                Crow[n * 16 + col] = acc[m][n][j] * rx * ryv[n];
        }
    }
}

extern "C" void kernel_launch(void* const* d_in, const int* in_sizes, int n_in,
                              void* d_out, int out_size, void* d_ws, size_t ws_size,
                              hipStream_t stream)
{
    const float* x = (const float*)d_in[0];
    const float* y = (const float*)d_in[1];
    float* out = (float*)d_out;

    char* ws = (char*)d_ws;
    unsigned short* xbf = (unsigned short*)ws;
    unsigned short* ybf = (unsigned short*)(ws + ((size_t)16 << 20));
    float* rxn = (float*)(ws + ((size_t)32 << 20));
    float* ryn = rxn + BATCH * NROW;

    static bool attr_done = false;
    if (!attr_done) {
        hipFuncSetAttribute((const void*)gemm_kernel,
                            hipFuncAttributeMaxDynamicSharedMemorySize, 131072);
        attr_done = true;
    }

    prep_kernel<<<dim3(4096, 2), 256, 0, stream>>>(x, y, xbf, ybf, rxn, ryn);
    gemm_kernel<<<dim3(512), 512, 131072, stream>>>(
        (const __bf16*)xbf, (const __bf16*)ybf, rxn, ryn, out);
}